// Round 5
// baseline (96.531 us; speedup 1.0000x reference)
//
#include <hip/hip_runtime.h>

// TripleGrainSeparatePermuter: per-row stable 3-way stream compaction.
// B=512 rows, N=4096 elements/row. 9 outputs of [B, N+1]=[512,4097] int32,
// concatenated flat in d_out in reference return order:
//   0: coarse_content  1: medium_content  2: fine_content
//   3: coarse_position 4: medium_position 5: fine_position
//   6: coarse_segment  7: medium_segment  8: fine_segment
//
// ROUND 5: DIRECT-SCATTER restructure (discriminating experiment).
// Rounds 1-4 showed the kernel is insensitive to every instruction-level
// lever (LDS bank conflicts, predicates, store scheduling, VGPR cap).
// Remaining hypotheses: (A) kernel already near its 14.7us traffic floor,
// dur_us dominated by harness fill + reset overhead; (B) kernel ~43us bound
// by the phase architecture (2 barriers, 16KB LDS round-trip, whole-block
// vmcnt drains). This version eliminates structure B entirely:
//   - after the count-combine, each thread knows the exact final slot of
//     each of its 4 tokens (class array + global stable rank) -> store
//     directly to global. Ranks are order-preserving, so a wave's stores
//     per class form consecutive runs -> well coalesced by HW.
//   - EOS/PAD slots are provably disjoint from data slots -> written in the
//     same phase, no second barrier.
//   - LDS shrinks 16.4KB -> 64B; one __syncthreads total; no gather phase.
// If dur_us is unchanged, hypothesis A is confirmed (roofline); if it drops,
// B was right; if it regresses, store coalescing is finally visible.

constexpr int N_TOK  = 4096;
constexpr int M_OUT  = N_TOK + 1;   // 4097
constexpr int TPB    = 1024;        // 16 waves/block, 2 blocks/CU (thread-limited)
constexpr int NWAVES = TPB / 64;
constexpr int EPT    = N_TOK / TPB; // 4 elements per thread (contiguous chunk)

constexpr int CONTENT_PAD = 1024, CONTENT_EOS = 1025;
// per-class position pad/eos: coarse 128/129, medium 256/257, fine 1024/1025
__device__ __constant__ int POS_PAD[3] = {128, 256, 1024};
__device__ __constant__ int POS_EOS[3] = {129, 257, 1025};

__global__ __launch_bounds__(TPB, 4) void
triple_grain_permute(const int* __restrict__ indices,
                     const int* __restrict__ grain,
                     int* __restrict__ out,
                     int batch) {
    const int b = blockIdx.x;
    const int t = threadIdx.x;
    const int lane = t & 63;
    const int wave = t >> 6;

    const int* idx_row = indices + (size_t)b * N_TOK;
    const int* g_row   = grain   + (size_t)b * N_TOK;

    __shared__ unsigned int s_wave_tot[NWAVES];

    // ---- issue input loads first ----
    const int4 gg = reinterpret_cast<const int4*>(g_row)[t];
    const int4 ii = reinterpret_cast<const int4*>(idx_row)[t];

    // ---- output geometry ----
    // Row start (in dwords) = (arr*512 + b)*4097 ≡ b (mod 4); peeling
    // (4 - (b&3)) & 3 leading slots makes the int4 body aligned for all arrays.
    const size_t ARR = (size_t)batch * M_OUT;   // elements per output array
    const int peel = (4 - (b & 3)) & 3;
    const int nch  = (M_OUT - peel) >> 2;       // int4 chunks (<= 1024)
    const int rem  = (M_OUT - peel) & 3;        // tail scalars
    const int s0   = peel + 4 * t;              // my chunk's first slot

    // ---- segment arrays: pure constants -> store immediately ----
#pragma unroll
    for (int c = 0; c < 3; ++c) {
        int* dst_s = out + (size_t)(6 + c) * ARR + (size_t)b * M_OUT;
        if (t < peel) dst_s[t] = c;
        if (t < nch)  *reinterpret_cast<int4*>(dst_s + s0) = make_int4(c, c, c, c);
        if (t < rem)  dst_s[M_OUT - rem + t] = c;
    }

    // ---- unpack loads ----
    const int gv[EPT] = {gg.x, gg.y, gg.z, gg.w};
    const int iv[EPT] = {ii.x, ii.y, ii.z, ii.w};
    const int elem0 = t * EPT;

    // ---- per-thread class counts (<=4), packed into 10-bit fields.
    // Wave-inclusive field max = 64*4 = 256 < 1024: no cross-field carry in u32.
    int c0 = 0, c1 = 0, c2 = 0;
#pragma unroll
    for (int j = 0; j < EPT; ++j) {
        c0 += (gv[j] == 0);
        c1 += (gv[j] == 1);
        c2 += (gv[j] == 2);
    }
    const unsigned int packed =
        (unsigned)c0 | ((unsigned)c1 << 10) | ((unsigned)c2 << 20);

    // ---- wave-64 inclusive scan, 32-bit (covers all 3 classes at once) ----
    unsigned int inc = packed;
#pragma unroll
    for (int off = 1; off < 64; off <<= 1) {
        unsigned int nb = (unsigned int)__shfl_up((int)inc, off, 64);
        if (lane >= off) inc += nb;
    }
    if (lane == 63) s_wave_tot[wave] = inc;
    __syncthreads();   // the ONLY barrier

    // ---- cross-wave combine (per-class, widened to 32-bit) ----
    int wp0 = 0, wp1 = 0, wp2 = 0, tot0 = 0, tot1 = 0, tot2 = 0;
#pragma unroll
    for (int w = 0; w < NWAVES; ++w) {
        const unsigned int v = s_wave_tot[w];
        const int f0 = v & 1023, f1 = (v >> 10) & 1023, f2 = (v >> 20) & 1023;
        if (w < wave) { wp0 += f0; wp1 += f1; wp2 += f2; }
        tot0 += f0; tot1 += f1; tot2 += f2;
    }
    const unsigned int exv = inc - packed;   // per-field exclusive (no borrow)
    int r0 = wp0 + (int)(exv & 1023);        // my global stable rank per class
    int r1 = wp1 + (int)((exv >> 10) & 1023);
    int r2 = wp2 + (int)((exv >> 20) & 1023);
    const int cnts[3] = {tot0, tot1, tot2};

    // ---- direct scatter of data tokens to their final global slots.
    // Ranks are order-preserving within the row, so a wave's 64 stores per
    // instruction form <=3 consecutive runs (one per class): well coalesced.
#pragma unroll
    for (int j = 0; j < EPT; ++j) {
        const int c = gv[j];
        const int rank = (c == 0) ? r0 : ((c == 1) ? r1 : r2);
        int* dc = out + (size_t)c       * ARR + (size_t)b * M_OUT;
        int* dp = out + (size_t)(3 + c) * ARR + (size_t)b * M_OUT;
        dc[rank] = iv[j];
        dp[rank] = elem0 + j;
        r0 += (c == 0);
        r1 += (c == 1);
        r2 += (c == 2);
    }

    // ---- EOS + PAD: slots >= cnt are disjoint from every data slot, so no
    //      synchronization with the scatter is needed ----
#pragma unroll
    for (int c = 0; c < 3; ++c) {
        int* dc = out + (size_t)c       * ARR + (size_t)b * M_OUT;
        int* dp = out + (size_t)(3 + c) * ARR + (size_t)b * M_OUT;
        const int cnt = cnts[c];
        const int peos = POS_EOS[c], ppad = POS_PAD[c];

        auto fillone = [&](int slot) {
            if (slot == cnt)      { dc[slot] = CONTENT_EOS; dp[slot] = peos; }
            else if (slot > cnt)  { dc[slot] = CONTENT_PAD; dp[slot] = ppad; }
            // slot < cnt: data, already written by the scatter
        };

        if (t < peel) fillone(t);
        if (t < nch) {
            if (s0 > cnt) {          // pure PAD chunk: vectorized constants
                *reinterpret_cast<int4*>(dc + s0) =
                    make_int4(CONTENT_PAD, CONTENT_PAD, CONTENT_PAD, CONTENT_PAD);
                *reinterpret_cast<int4*>(dp + s0) =
                    make_int4(ppad, ppad, ppad, ppad);
            } else if (s0 + 3 >= cnt) {   // boundary chunk: contains EOS
                fillone(s0 + 0);
                fillone(s0 + 1);
                fillone(s0 + 2);
                fillone(s0 + 3);
            }
            // s0+3 < cnt: all-data chunk, nothing to do
        }
        if (t < rem) fillone(M_OUT - rem + t);
    }
}

extern "C" void kernel_launch(void* const* d_in, const int* in_sizes, int n_in,
                              void* d_out, int out_size, void* d_ws, size_t ws_size,
                              hipStream_t stream) {
    const int* indices = (const int*)d_in[0];
    const int* grain   = (const int*)d_in[1];
    int* out = (int*)d_out;

    const int batch = in_sizes[0] / N_TOK;  // 512
    triple_grain_permute<<<batch, TPB, 0, stream>>>(indices, grain, out, batch);
}

// Round 6
// 93.198 us; speedup vs baseline: 1.0358x; 1.0358x over previous
//
#include <hip/hip_runtime.h>

// TripleGrainSeparatePermuter: per-row stable 3-way stream compaction.
// B=512 rows, N=4096 elements/row. 9 outputs of [B, N+1]=[512,4097] int32,
// concatenated flat in d_out in reference return order:
//   0: coarse_content  1: medium_content  2: fine_content
//   3: coarse_position 4: medium_position 5: fine_position
//   6: coarse_segment  7: medium_segment  8: fine_segment
//
// ROUND 6: REVERT to the round-4 kernel -- the measured best (90.62 us).
// Session findings (rounds 0-5):
//  - The kernel is store-BW-bound at ~16-19us vs a 14.7us traffic floor
//    (75.5MB out + 16.8MB in @ 6.36 TB/s, the rate the harness fill proves
//    on this exact buffer). dur_us' other ~73us is harness-fixed: 47.5us
//    output re-poison fill + ~25us of tiny reset dispatches.
//  - Only store-efficiency edits ever moved dur_us: direct-scatter with
//    scalar stores (R5) cost +6us; all overlapped-work edits (bank-conflict
//    swizzle, PAD predicate shortcut, store hoisting, VGPR cap, removing a
//    barrier + all LDS data staging) were neutral -- they hide under stores.
//  - LDS-gather + coalesced int4 write-out is the winning architecture.
//
// Structure: load -> packed 3-class wave scan -> cross-wave combine ->
// swizzled LDS scatter -> barrier -> unified vectorized write-out.

constexpr int N_TOK  = 4096;
constexpr int M_OUT  = N_TOK + 1;   // 4097
constexpr int TPB    = 1024;        // 16 waves/block
constexpr int NWAVES = TPB / 64;
constexpr int EPT    = N_TOK / TPB; // 4 elements per thread (contiguous chunk)

constexpr int CONTENT_PAD = 1024, CONTENT_EOS = 1025;
// per-class position pad/eos: coarse 128/129, medium 256/257, fine 1024/1025
__device__ __constant__ int POS_PAD[3] = {128, 256, 1024};
__device__ __constant__ int POS_EOS[3] = {129, 257, 1025};

// Bank swizzle: XOR bits [4:2] with bits [7:5]. Involution, bijective on
// [0,4096), permutes within each aligned 32-dword block (so scatter-write
// locality is preserved). Write-phase read lane t -> addrs base+4t+j: the 8
// lanes sharing (t mod 8) span 8 consecutive values of addr bits [7:5], so
// the XOR gives them 8 distinct bank groups -> conflict-free.
__device__ __forceinline__ int swz(int a) { return a ^ ((a >> 3) & 0x1C); }

__global__ __launch_bounds__(TPB, 4) void
triple_grain_permute(const int* __restrict__ indices,
                     const int* __restrict__ grain,
                     int* __restrict__ out,
                     int batch) {
    const int b = blockIdx.x;
    const int t = threadIdx.x;
    const int lane = t & 63;
    const int wave = t >> 6;

    const int* idx_row = indices + (size_t)b * N_TOK;
    const int* g_row   = grain   + (size_t)b * N_TOK;

    // packed per-token word: content (bits 0..11, values<=1023) | pos<<12 (<=4095)
    __shared__ int s_packed[N_TOK];
    __shared__ unsigned int s_wave_tot[NWAVES];

    // ---- issue input loads first ----
    const int4 gg = reinterpret_cast<const int4*>(g_row)[t];
    const int4 ii = reinterpret_cast<const int4*>(idx_row)[t];

    // ---- output geometry ----
    // Row start (in dwords) = (arr*512 + b)*4097 ≡ b (mod 4); peeling
    // (4 - (b&3)) & 3 leading slots makes the body int4-aligned for all arrays.
    const size_t ARR = (size_t)batch * M_OUT;   // elements per output array
    const int peel = (4 - (b & 3)) & 3;
    const int nch  = (M_OUT - peel) >> 2;       // int4 chunks (<= 1024)
    const int rem  = (M_OUT - peel) & 3;        // tail scalars
    const int s0   = peel + 4 * t;              // my chunk's first slot

    // ---- segment arrays: pure constants, no dependencies -> store NOW so
    //      they drain during the scan/combine/scatter phases ----
#pragma unroll
    for (int c = 0; c < 3; ++c) {
        int* dst_s = out + (size_t)(6 + c) * ARR + (size_t)b * M_OUT;
        if (t < peel) dst_s[t] = c;
        if (t < nch)  *reinterpret_cast<int4*>(dst_s + s0) = make_int4(c, c, c, c);
        if (t < rem)  dst_s[M_OUT - rem + t] = c;
    }

    // ---- unpack loads ----
    int gv[EPT] = {gg.x, gg.y, gg.z, gg.w};
    const int elem0 = t * EPT;
    int pv[EPT] = {ii.x | (elem0 << 12),
                   ii.y | ((elem0 + 1) << 12),
                   ii.z | ((elem0 + 2) << 12),
                   ii.w | ((elem0 + 3) << 12)};

    // ---- per-thread class counts (<=4), packed into 10-bit fields.
    // Wave-inclusive field max = 64*4 = 256 < 1024: no cross-field carry in u32.
    int c0 = 0, c1 = 0, c2 = 0;
#pragma unroll
    for (int j = 0; j < EPT; ++j) {
        c0 += (gv[j] == 0);
        c1 += (gv[j] == 1);
        c2 += (gv[j] == 2);
    }
    unsigned int packed = (unsigned)c0 | ((unsigned)c1 << 10) | ((unsigned)c2 << 20);

    // ---- wave-64 inclusive scan, 32-bit (covers all 3 classes at once) ----
    unsigned int inc = packed;
#pragma unroll
    for (int off = 1; off < 64; off <<= 1) {
        unsigned int nb = (unsigned int)__shfl_up((int)inc, off, 64);
        if (lane >= off) inc += nb;
    }
    if (lane == 63) s_wave_tot[wave] = inc;
    __syncthreads();

    // ---- cross-wave combine (per-class, 32-bit fields widened here) ----
    int wp0 = 0, wp1 = 0, wp2 = 0, tot0 = 0, tot1 = 0, tot2 = 0;
#pragma unroll
    for (int w = 0; w < NWAVES; ++w) {
        const unsigned int v = s_wave_tot[w];
        const int f0 = v & 1023, f1 = (v >> 10) & 1023, f2 = (v >> 20) & 1023;
        if (w < wave) { wp0 += f0; wp1 += f1; wp2 += f2; }
        tot0 += f0; tot1 += f1; tot2 += f2;
    }
    const unsigned int exv = inc - packed;   // per-field exclusive (no borrow)
    const int o0 = wp0 + (int)(exv & 1023);
    const int o1 = wp1 + (int)((exv >> 10) & 1023);
    const int o2 = wp2 + (int)((exv >> 20) & 1023);
    const int cnt0 = tot0, cnt1 = tot1, cnt2 = tot2;

    // compacted class segments laid back-to-back in LDS
    const int base0 = 0, base1 = cnt0, base2 = cnt0 + cnt1;

    // ---- scatter my chunk into (swizzled) LDS (stable: contiguous chunk) ----
    int d0 = base0 + o0, d1 = base1 + o1, d2 = base2 + o2;
#pragma unroll
    for (int j = 0; j < EPT; ++j) {
        const int c = gv[j];
        const int dst = (c == 0) ? d0 : ((c == 1) ? d1 : d2);
        s_packed[swz(dst)] = pv[j];
        d0 += (c == 0);
        d1 += (c == 1);
        d2 += (c == 2);
    }
    __syncthreads();

    // ---- vectorized coalesced write-out (content + position) ----
    const int bases[3] = {base0, base1, base2};
    const int cnts[3]  = {cnt0, cnt1, cnt2};

#pragma unroll
    for (int c = 0; c < 3; ++c) {
        int* dst_c = out + (size_t)c       * ARR + (size_t)b * M_OUT;
        int* dst_p = out + (size_t)(3 + c) * ARR + (size_t)b * M_OUT;
        const int cnt = cnts[c];
        const int base = bases[c];
        const int peos = POS_EOS[c], ppad = POS_PAD[c];

        auto elem = [&](int slot, int& vc, int& vp) {
            int a = base + slot;
            a = (a > N_TOK - 1) ? (N_TOK - 1) : a;   // pad lanes read junk, discarded
            const int pk = s_packed[swz(a)];
            vc = (slot < cnt) ? (pk & 0xFFF) : ((slot == cnt) ? CONTENT_EOS : CONTENT_PAD);
            vp = (slot < cnt) ? (pk >> 12)   : ((slot == cnt) ? peos : ppad);
        };

        if (t < peel) {                      // leading scalars to alignment
            int vc, vp;
            elem(t, vc, vp);
            dst_c[t] = vc; dst_p[t] = vp;
        }
        if (t < nch) {                       // aligned int4 body, one chunk/thread
            if (s0 + 3 < cnt) {
                // pure data chunk: no predicates, conflict-free swizzled reads
                const int a = base + s0;
                const int p0 = s_packed[swz(a)];
                const int p1 = s_packed[swz(a + 1)];
                const int p2 = s_packed[swz(a + 2)];
                const int p3 = s_packed[swz(a + 3)];
                *reinterpret_cast<int4*>(dst_c + s0) =
                    make_int4(p0 & 0xFFF, p1 & 0xFFF, p2 & 0xFFF, p3 & 0xFFF);
                *reinterpret_cast<int4*>(dst_p + s0) =
                    make_int4(p0 >> 12, p1 >> 12, p2 >> 12, p3 >> 12);
            } else if (s0 > cnt) {
                // pure PAD chunk: constants only, no LDS traffic
                *reinterpret_cast<int4*>(dst_c + s0) =
                    make_int4(CONTENT_PAD, CONTENT_PAD, CONTENT_PAD, CONTENT_PAD);
                *reinterpret_cast<int4*>(dst_p + s0) =
                    make_int4(ppad, ppad, ppad, ppad);
            } else {
                // boundary chunk (contains EOS): full predicate path
                int4 vc4, vp4;
                elem(s0 + 0, vc4.x, vp4.x);
                elem(s0 + 1, vc4.y, vp4.y);
                elem(s0 + 2, vc4.z, vp4.z);
                elem(s0 + 3, vc4.w, vp4.w);
                *reinterpret_cast<int4*>(dst_c + s0) = vc4;
                *reinterpret_cast<int4*>(dst_p + s0) = vp4;
            }
        }
        if (t < rem) {                       // tail scalars
            const int slot = M_OUT - rem + t;
            int vc, vp;
            elem(slot, vc, vp);
            dst_c[slot] = vc; dst_p[slot] = vp;
        }
    }
}

extern "C" void kernel_launch(void* const* d_in, const int* in_sizes, int n_in,
                              void* d_out, int out_size, void* d_ws, size_t ws_size,
                              hipStream_t stream) {
    const int* indices = (const int*)d_in[0];
    const int* grain   = (const int*)d_in[1];
    int* out = (int*)d_out;

    const int batch = in_sizes[0] / N_TOK;  // 512
    triple_grain_permute<<<batch, TPB, 0, stream>>>(indices, grain, out, batch);
}